// Round 2
// baseline (663.490 us; speedup 1.0000x reference)
//
#include <hip/hip_runtime.h>
#include <math.h>

#define S_DIM 4096
#define B_DIM 2
#define D_DIM 2048
#define NP    8192            // n*D  (K dimension)
#define NPAIR 8192            // S*B  (M dimension)
#define PLANE ((size_t)NPAIR * D_DIM)   // 16,777,216 elements per [S,B,D] plane

// itertools.permutations(range(4)) — lexicographic order.
// perms[r] = eye[list(p)] -> row i is e_{p[i]} -> H[i][j] += coeff[r] * (p[i]==j)
__device__ constexpr int PT[24][4] = {
    {0,1,2,3},{0,1,3,2},{0,2,1,3},{0,2,3,1},{0,3,1,2},{0,3,2,1},
    {1,0,2,3},{1,0,3,2},{1,2,0,3},{1,2,3,0},{1,3,0,2},{1,3,2,0},
    {2,0,1,3},{2,0,3,1},{2,1,0,3},{2,1,3,0},{2,3,0,1},{2,3,1,0},
    {3,0,1,2},{3,0,2,1},{3,1,0,2},{3,1,2,0},{3,2,0,1},{3,2,1,0}
};

// ---------------------------------------------------------------------------
// Kernel 1: partial dots  raw[js][pair][k] = sum_{e in js-range} x[pair,e] *
// (1+nw[e]) * W[e][k]   (k<28: dynamic_alpha_fn, k>=28: dynamic_beta_fn)
// plus partial sum-of-squares ssqp[js][pair].
// Block: 256 thr, M-tile 32 pairs, K-split 4 (js == stream index j).
// ---------------------------------------------------------------------------
#define MT 32
#define CK 128

__global__ __launch_bounds__(256) void k1_partial(
    const float* __restrict__ X,     // [4][NPAIR][D]
    const float* __restrict__ Wa,    // [NP][28]
    const float* __restrict__ Wb,    // [NP][4]
    const float* __restrict__ nw,    // [NP]
    float* __restrict__ partials,    // [4][NPAIR][32]
    float* __restrict__ ssqp)        // [4][NPAIR]
{
    __shared__ float Xs[CK][MT + 1];   // [e][m], stride 33 floats
    __shared__ float Ws[CK][32];       // [e][k]

    const int bid = blockIdx.x;
    const int js  = bid & 3;           // which j (K-split)
    const int p0  = (bid >> 2) * MT;   // first pair of tile
    const int t   = threadIdx.x;
    const int m   = t & 31;            // pair within tile
    const int cg  = t >> 5;            // column group (0..7) -> cols cg*4..cg*4+3

    float acc0 = 0.f, acc1 = 0.f, acc2 = 0.f, acc3 = 0.f, ssq = 0.f;
    const float* Xb = X + (size_t)js * PLANE + (size_t)p0 * D_DIM;

    for (int dc = 0; dc < D_DIM; dc += CK) {
        __syncthreads();
        // ---- stage X tile (transposed): 32 rows x 128 floats, coalesced f4
        #pragma unroll
        for (int q = 0; q < 4; ++q) {
            const int row = q * 8 + (t >> 5);
            const int d4  = t & 31;
            const float4 v = *reinterpret_cast<const float4*>(
                Xb + (size_t)row * D_DIM + dc + d4 * 4);
            Xs[d4 * 4 + 0][row] = v.x;
            Xs[d4 * 4 + 1][row] = v.y;
            Xs[d4 * 4 + 2][row] = v.z;
            Xs[d4 * 4 + 3][row] = v.w;
        }
        // ---- stage weight tile with (1+nw) folded in
        #pragma unroll
        for (int q = 0; q < 4; ++q) {
            const int el = q * 32 + (t >> 3);       // e within chunk
            const int c  = (t & 7) * 4;             // col 0,4,...,28
            const int eg = js * 2048 + dc + el;     // global e
            const float s = 1.0f + nw[eg];
            float4 w;
            if (c < 28)
                w = *reinterpret_cast<const float4*>(Wa + (size_t)eg * 28 + c);
            else
                w = *reinterpret_cast<const float4*>(Wb + (size_t)eg * 4);
            w.x *= s; w.y *= s; w.z *= s; w.w *= s;
            *reinterpret_cast<float4*>(&Ws[el][c]) = w;
        }
        __syncthreads();
        // ---- accumulate
        #pragma unroll 8
        for (int e = 0; e < CK; ++e) {
            const float x = Xs[e][m];
            const float4 w = *reinterpret_cast<const float4*>(&Ws[e][cg * 4]);
            acc0 = fmaf(x, w.x, acc0);
            acc1 = fmaf(x, w.y, acc1);
            acc2 = fmaf(x, w.z, acc2);
            acc3 = fmaf(x, w.w, acc3);
            ssq  = fmaf(x, x, ssq);      // every thread; only cg==0 writes
        }
    }

    float* pr = partials + ((size_t)js * NPAIR + (p0 + m)) * 32 + cg * 4;
    pr[0] = acc0; pr[1] = acc1; pr[2] = acc2; pr[3] = acc3;
    if (cg == 0) ssqp[(size_t)js * NPAIR + p0 + m] = ssq;
}

// ---------------------------------------------------------------------------
// Kernel 2: per-pair gating. One thread per pair.
// gate[p][0..3]=alpha, [4..19]=H(row-major 4x4), [20..23]=beta  (stride 32)
// ---------------------------------------------------------------------------
__global__ __launch_bounds__(256) void k2_gate(
    const float* __restrict__ partials,  // [4][NPAIR][32]
    const float* __restrict__ ssqp,      // [4][NPAIR]
    const float* __restrict__ sa,        // [28]
    const float* __restrict__ sb,        // [4]
    const float* __restrict__ ps_,
    const float* __restrict__ rs_,
    const float* __restrict__ hs_,
    float* __restrict__ gate)            // [NPAIR][32]
{
    const int p = blockIdx.x * 256 + threadIdx.x;

    float raw[32];
    #pragma unroll
    for (int k = 0; k < 32; ++k) raw[k] = 0.f;
    #pragma unroll
    for (int js = 0; js < 4; ++js) {
        const float* pr = partials + ((size_t)js * NPAIR + p) * 32;
        #pragma unroll
        for (int k4 = 0; k4 < 8; ++k4) {
            const float4 v = *reinterpret_cast<const float4*>(pr + k4 * 4);
            raw[k4*4+0] += v.x; raw[k4*4+1] += v.y;
            raw[k4*4+2] += v.z; raw[k4*4+3] += v.w;
        }
    }
    const float ssq = ssqp[p] + ssqp[NPAIR + p] + ssqp[2*NPAIR + p] + ssqp[3*NPAIR + p];
    const float rms = rsqrtf(ssq * (1.0f / NP) + 1e-6f);
    const float ps = ps_[0], rs = rs_[0], hs = hs_[0];

    float alpha[4];
    #pragma unroll
    for (int i = 0; i < 4; ++i)
        alpha[i] = 1.0f / (1.0f + __expf(-(ps * (rms * raw[i]) + sa[i])));

    float v[24], mx = -1e30f;
    #pragma unroll
    for (int r = 0; r < 24; ++r) {
        v[r] = rs * (rms * raw[4 + r]) + sa[4 + r];
        mx = fmaxf(mx, v[r]);
    }
    float sum = 0.f;
    #pragma unroll
    for (int r = 0; r < 24; ++r) { v[r] = __expf(v[r] - mx); sum += v[r]; }
    const float inv = 1.0f / sum;

    float H[16];
    #pragma unroll
    for (int i = 0; i < 16; ++i) H[i] = 0.f;
    #pragma unroll
    for (int r = 0; r < 24; ++r) {
        const float c = v[r] * inv;
        #pragma unroll
        for (int i = 0; i < 4; ++i) H[i * 4 + PT[r][i]] += c;   // constant idx
    }

    float beta[4];
    #pragma unroll
    for (int i = 0; i < 4; ++i)
        beta[i] = 2.0f / (1.0f + __expf(-(hs * (rms * raw[28 + i]) + sb[i])));

    float4* g4 = reinterpret_cast<float4*>(gate + (size_t)p * 32);
    g4[0] = make_float4(alpha[0], alpha[1], alpha[2], alpha[3]);
    g4[1] = make_float4(H[0],  H[1],  H[2],  H[3]);
    g4[2] = make_float4(H[4],  H[5],  H[6],  H[7]);
    g4[3] = make_float4(H[8],  H[9],  H[10], H[11]);
    g4[4] = make_float4(H[12], H[13], H[14], H[15]);
    g4[5] = make_float4(beta[0], beta[1], beta[2], beta[3]);
}

// ---------------------------------------------------------------------------
// Kernel 3: streaming recombine.  Block handles (pair p, half h): 256 thr x f4
// out[0] = sum_n alpha[n] X[n] ; out[1+i] = beta[i]*x_out + sum_j H[i][j] X[j]
// ---------------------------------------------------------------------------
__global__ __launch_bounds__(256) void k3_out(
    const float* __restrict__ X,     // [4][NPAIR][D]
    const float* __restrict__ xo,    // [NPAIR][D]
    const float* __restrict__ gate,  // [NPAIR][32]
    float* __restrict__ out)         // [5][NPAIR][D]
{
    const int bid = blockIdx.x;
    const int p = bid >> 1;
    const int h = bid & 1;
    const int d = h * 1024 + threadIdx.x * 4;

    __shared__ float g[24];
    if (threadIdx.x < 6) {
        reinterpret_cast<float4*>(g)[threadIdx.x] =
            reinterpret_cast<const float4*>(gate + (size_t)p * 32)[threadIdx.x];
    }
    __syncthreads();

    const size_t base = (size_t)p * D_DIM + d;
    const float4 x0 = *reinterpret_cast<const float4*>(X + 0 * PLANE + base);
    const float4 x1 = *reinterpret_cast<const float4*>(X + 1 * PLANE + base);
    const float4 x2 = *reinterpret_cast<const float4*>(X + 2 * PLANE + base);
    const float4 x3 = *reinterpret_cast<const float4*>(X + 3 * PLANE + base);
    const float4 xv = *reinterpret_cast<const float4*>(xo + base);

    const float a0 = g[0], a1 = g[1], a2 = g[2], a3 = g[3];
    float4 o;
    o.x = fmaf(a0,x0.x, fmaf(a1,x1.x, fmaf(a2,x2.x, a3*x3.x)));
    o.y = fmaf(a0,x0.y, fmaf(a1,x1.y, fmaf(a2,x2.y, a3*x3.y)));
    o.z = fmaf(a0,x0.z, fmaf(a1,x1.z, fmaf(a2,x2.z, a3*x3.z)));
    o.w = fmaf(a0,x0.w, fmaf(a1,x1.w, fmaf(a2,x2.w, a3*x3.w)));
    *reinterpret_cast<float4*>(out + 0 * PLANE + base) = o;

    #pragma unroll
    for (int i = 0; i < 4; ++i) {
        const float h0 = g[4 + i*4 + 0], h1 = g[4 + i*4 + 1];
        const float h2 = g[4 + i*4 + 2], h3 = g[4 + i*4 + 3];
        const float bi = g[20 + i];
        float4 r;
        r.x = fmaf(bi,xv.x, fmaf(h0,x0.x, fmaf(h1,x1.x, fmaf(h2,x2.x, h3*x3.x))));
        r.y = fmaf(bi,xv.y, fmaf(h0,x0.y, fmaf(h1,x1.y, fmaf(h2,x2.y, h3*x3.y))));
        r.z = fmaf(bi,xv.z, fmaf(h0,x0.z, fmaf(h1,x1.z, fmaf(h2,x2.z, h3*x3.z))));
        r.w = fmaf(bi,xv.w, fmaf(h0,x0.w, fmaf(h1,x1.w, fmaf(h2,x2.w, h3*x3.w))));
        *reinterpret_cast<float4*>(out + (size_t)(1 + i) * PLANE + base) = r;
    }
}

// ---------------------------------------------------------------------------
extern "C" void kernel_launch(void* const* d_in, const int* in_sizes, int n_in,
                              void* d_out, int out_size, void* d_ws, size_t ws_size,
                              hipStream_t stream)
{
    const float* X   = (const float*)d_in[0];   // [4,4096,2,2048]
    const float* xo  = (const float*)d_in[1];   // [4096,2,2048]
    const float* nw  = (const float*)d_in[2];   // [8192]
    const float* Wa  = (const float*)d_in[3];   // [8192,28]
    const float* sa  = (const float*)d_in[4];   // [28]
    const float* Wb  = (const float*)d_in[5];   // [8192,4]
    const float* sb  = (const float*)d_in[6];   // [4]
    const float* ps  = (const float*)d_in[7];   // [1]
    const float* rs  = (const float*)d_in[8];   // [1]
    const float* hs  = (const float*)d_in[9];   // [1]
    float* out = (float*)d_out;

    float* wsf      = (float*)d_ws;
    float* partials = wsf;                          // 4*8192*32 = 1,048,576
    float* ssqp     = wsf + 1048576;                // 4*8192    =    32,768
    float* gate     = wsf + 1048576 + 32768;        // 8192*32   =   262,144

    // 1) partial dots + ssq:  (8192/32 pair-tiles) * 4 K-splits
    hipLaunchKernelGGL(k1_partial, dim3((NPAIR / MT) * 4), dim3(256), 0, stream,
                       X, Wa, Wb, nw, partials, ssqp);
    // 2) gating (one thread per pair)
    hipLaunchKernelGGL(k2_gate, dim3(NPAIR / 256), dim3(256), 0, stream,
                       partials, ssqp, sa, sb, ps, rs, hs, gate);
    // 3) streaming recombine
    hipLaunchKernelGGL(k3_out, dim3(NPAIR * 2), dim3(256), 0, stream,
                       X, xo, gate, out);
}